// Round 1
// baseline (378.682 us; speedup 1.0000x reference)
//
#include <hip/hip_runtime.h>

#define B 4
#define C 128
#define H 128
#define W 128
#define HW (H * W)
#define KK 9
#define MID 25

// Workspace layout (floats):
//   [0, 512)        xm_sum  (B*C)  -- per-channel pixel sums (atomic), zeroed by memset
//   [1024, 5632)    ch      (B*C*KK) channel filter
//   [8192, 598016)  S       (B*KK*HW) spatial filter
#define WS_XM 0
#define WS_CH 1024
#define WS_S  8192

// K1: fused global-mean accumulation + spatial filter (sigmoid(x . Ws + bs))
// grid (HW/256, B), block 256. One thread per pixel, loop over channels.
__global__ __launch_bounds__(256) void k_mean_spatial(
    const float* __restrict__ x, const float* __restrict__ Ws,
    const float* __restrict__ bs, float* __restrict__ xm_sum,
    float* __restrict__ S)
{
    const int tid = threadIdx.x;
    const int b = blockIdx.y;
    const int p = blockIdx.x * 256 + tid;
    const float* xb = x + (size_t)b * C * HW + p;

    float acc[KK];
#pragma unroll
    for (int k = 0; k < KK; ++k) acc[k] = bs[k];

    const int lane = tid & 63;
    for (int c = 0; c < C; ++c) {
        float v = xb[(size_t)c * HW];
#pragma unroll
        for (int k = 0; k < KK; ++k)
            acc[k] = fmaf(v, Ws[k * C + c], acc[k]);  // uniform index -> scalar load
        // wave-level reduction of v for the per-channel mean
        float s = v;
#pragma unroll
        for (int off = 32; off > 0; off >>= 1) s += __shfl_down(s, off, 64);
        if (lane == 0) atomicAdd(&xm_sum[b * C + c], s);
    }

#pragma unroll
    for (int k = 0; k < KK; ++k) {
        float sg = 1.0f / (1.0f + __expf(-acc[k]));
        S[((size_t)(b * KK + k)) * HW + p] = sg;  // coalesced along p
    }
}

// K2: channel MLP. Single block, 256 threads.
// hid = relu(mean @ W1^T + b1); ch = sigmoid(hid @ W2^T + b2)
__global__ __launch_bounds__(256) void k_mlp(
    const float* __restrict__ xm_sum, const float* __restrict__ W1,
    const float* __restrict__ b1, const float* __restrict__ W2,
    const float* __restrict__ b2, float* __restrict__ ch)
{
    __shared__ float xmean[B * C];
    __shared__ float hid[B * MID];
    const int tid = threadIdx.x;

    for (int i = tid; i < B * C; i += 256)
        xmean[i] = xm_sum[i] * (1.0f / HW);
    __syncthreads();

    if (tid < B * MID) {
        const int b = tid / MID, m = tid % MID;
        float a = b1[m];
        for (int c = 0; c < C; ++c)
            a = fmaf(xmean[b * C + c], W1[m * C + c], a);
        hid[tid] = fmaxf(a, 0.0f);
    }
    __syncthreads();

    for (int idx = tid; idx < B * C * KK; idx += 256) {
        const int b = idx / (C * KK);
        const int o = idx % (C * KK);
        float a = b2[o];
#pragma unroll
        for (int m = 0; m < MID; ++m)
            a = fmaf(hid[b * MID + m], W2[o * MID + m], a);
        ch[idx] = 1.0f / (1.0f + __expf(-a));
    }
}

// K3: dynamic 3x3 conv. out[b,c,h,w] = sum_k x[b,c,h+di,w+dj] * S[b,k,h,w] * ch[b,c,k]
// grid (HW/256, B, 2), block 256. One thread per pixel; z splits the channel loop.
__global__ __launch_bounds__(256) void k_conv(
    const float* __restrict__ x, const float* __restrict__ S,
    const float* __restrict__ ch, float* __restrict__ out)
{
    const int tid = threadIdx.x;
    const int b = blockIdx.y;
    const int p = blockIdx.x * 256 + tid;
    const int h = p / W, w = p % W;

    // 9 spatial-filter values for this pixel; fold tap validity into them.
    float sv[KK];
    int off[KK];
    const float* Sb = S + (size_t)b * KK * HW + p;
#pragma unroll
    for (int k = 0; k < KK; ++k) {
        const int di = k / 3 - 1, dj = k % 3 - 1;
        const int hh = h + di, ww = w + dj;
        const bool valid = (hh >= 0) & (hh < H) & (ww >= 0) & (ww < W);
        const int hc = min(max(hh, 0), H - 1);
        const int wc = min(max(ww, 0), W - 1);
        off[k] = hc * W + wc;                // clamped (safe) address
        sv[k] = valid ? Sb[(size_t)k * HW] : 0.0f;  // invalid taps contribute 0
    }

    const int c0 = blockIdx.z * (C / 2);
    const float* xb = x + (size_t)b * C * HW;
    const float* chb = ch + b * C * KK;
    float* ob = out + (size_t)b * C * HW;

    for (int c = c0; c < c0 + C / 2; ++c) {
        const float* xc = xb + (size_t)c * HW;
        float acc = 0.0f;
#pragma unroll
        for (int k = 0; k < KK; ++k) {
            // chb index uniform across lanes -> scalar load
            acc = fmaf(xc[off[k]], sv[k] * chb[c * KK + k], acc);
        }
        ob[(size_t)c * HW + p] = acc;  // coalesced along p
    }
}

extern "C" void kernel_launch(void* const* d_in, const int* in_sizes, int n_in,
                              void* d_out, int out_size, void* d_ws, size_t ws_size,
                              hipStream_t stream) {
    (void)in_sizes; (void)n_in; (void)out_size; (void)ws_size;
    const float* x  = (const float*)d_in[0];
    const float* Ws = (const float*)d_in[1];
    const float* bs = (const float*)d_in[2];
    const float* W1 = (const float*)d_in[3];
    const float* b1 = (const float*)d_in[4];
    const float* W2 = (const float*)d_in[5];
    const float* b2 = (const float*)d_in[6];
    float* out = (float*)d_out;
    float* ws  = (float*)d_ws;

    float* xm_sum = ws + WS_XM;
    float* ch     = ws + WS_CH;
    float* S      = ws + WS_S;

    // zero the atomic mean accumulators (ws is poisoned 0xAA each call)
    hipMemsetAsync(xm_sum, 0, B * C * sizeof(float), stream);

    k_mean_spatial<<<dim3(HW / 256, B), 256, 0, stream>>>(x, Ws, bs, xm_sum, S);
    k_mlp<<<1, 256, 0, stream>>>(xm_sum, W1, b1, W2, b2, ch);
    k_conv<<<dim3(HW / 256, B, 2), 256, 0, stream>>>(x, S, ch, out);
}

// Round 2
// 150.113 us; speedup vs baseline: 2.5226x; 2.5226x over previous
//
#include <hip/hip_runtime.h>

#define B 4
#define C 128
#define H 128
#define W 128
#define HW (H * W)
#define KK 9
#define MID 25

// Workspace layout (floats):
//   [0, 512)        xm      (B*C)   per-channel means (written directly, no atomics)
//   [1024, 5632)    ch      (B*C*KK) channel filter
//   [8192, 598016)  S       (B*KK*HW) spatial filter
#define WS_XM 0
#define WS_CH 1024
#define WS_S  8192

// K0: per-(b,c)-plane mean. grid (C, B), block 256. float4 loads, LDS reduce.
__global__ __launch_bounds__(256) void k_mean(
    const float* __restrict__ x, float* __restrict__ xm)
{
    const int c = blockIdx.x, b = blockIdx.y;
    const float4* plane = (const float4*)(x + ((size_t)b * C + c) * HW);
    float s = 0.0f;
#pragma unroll
    for (int i = 0; i < 16; ++i) {
        float4 v = plane[i * 256 + threadIdx.x];
        s += (v.x + v.y) + (v.z + v.w);
    }
#pragma unroll
    for (int off = 32; off > 0; off >>= 1) s += __shfl_down(s, off, 64);
    __shared__ float red[4];
    if ((threadIdx.x & 63) == 0) red[threadIdx.x >> 6] = s;
    __syncthreads();
    if (threadIdx.x == 0)
        xm[b * C + c] = ((red[0] + red[1]) + (red[2] + red[3])) * (1.0f / HW);
}

// K1: spatial filter sigmoid(x . Ws + bs). grid (HW/256, B), block 256.
// One thread per pixel, loop over channels: 1 coalesced load + 9 FMA each.
__global__ __launch_bounds__(256) void k_spatial(
    const float* __restrict__ x, const float* __restrict__ Ws,
    const float* __restrict__ bs, float* __restrict__ S)
{
    const int tid = threadIdx.x;
    const int b = blockIdx.y;
    const int p = blockIdx.x * 256 + tid;
    const float* xb = x + (size_t)b * C * HW + p;

    float acc[KK];
#pragma unroll
    for (int k = 0; k < KK; ++k) acc[k] = bs[k];

#pragma unroll 4
    for (int c = 0; c < C; ++c) {
        float v = xb[(size_t)c * HW];
#pragma unroll
        for (int k = 0; k < KK; ++k)
            acc[k] = fmaf(v, Ws[k * C + c], acc[k]);  // uniform index -> scalar load
    }

#pragma unroll
    for (int k = 0; k < KK; ++k) {
        float sg = 1.0f / (1.0f + __expf(-acc[k]));
        S[((size_t)(b * KK + k)) * HW + p] = sg;  // coalesced along p
    }
}

// K2: channel MLP. Single block, 512 threads.
// hid = relu(mean @ W1^T + b1); ch = sigmoid(hid @ W2^T + b2)
__global__ __launch_bounds__(512) void k_mlp(
    const float* __restrict__ xm, const float* __restrict__ W1,
    const float* __restrict__ b1, const float* __restrict__ W2,
    const float* __restrict__ b2, float* __restrict__ ch)
{
    __shared__ float xmean[B * C];
    __shared__ float hid[B * MID];
    const int tid = threadIdx.x;

    if (tid < B * C) xmean[tid] = xm[tid];
    __syncthreads();

    if (tid < B * MID) {
        const int b = tid / MID, m = tid % MID;
        float a = b1[m];
        for (int c = 0; c < C; ++c)
            a = fmaf(xmean[b * C + c], W1[m * C + c], a);
        hid[tid] = fmaxf(a, 0.0f);
    }
    __syncthreads();

    for (int idx = tid; idx < B * C * KK; idx += 512) {
        const int b = idx / (C * KK);
        const int o = idx % (C * KK);
        float a = b2[o];
#pragma unroll
        for (int m = 0; m < MID; ++m)
            a = fmaf(hid[b * MID + m], W2[o * MID + m], a);
        ch[idx] = 1.0f / (1.0f + __expf(-a));
    }
}

// K3: dynamic 3x3 conv. out[b,c,h,w] = sum_k x[b,c,h+di,w+dj] * S[b,k,h,w] * ch[b,c,k]
// grid (HW/256, B, 4), block 256. One thread per pixel; z splits channels (32 each).
__global__ __launch_bounds__(256) void k_conv(
    const float* __restrict__ x, const float* __restrict__ S,
    const float* __restrict__ ch, float* __restrict__ out)
{
    const int tid = threadIdx.x;
    const int b = blockIdx.y;
    const int p = blockIdx.x * 256 + tid;
    const int h = p / W, w = p % W;

    // 9 spatial-filter values for this pixel; fold tap validity into them.
    float sv[KK];
    int off[KK];
    const float* Sb = S + (size_t)b * KK * HW + p;
#pragma unroll
    for (int k = 0; k < KK; ++k) {
        const int di = k / 3 - 1, dj = k % 3 - 1;
        const int hh = h + di, ww = w + dj;
        const bool valid = (hh >= 0) & (hh < H) & (ww >= 0) & (ww < W);
        const int hc = min(max(hh, 0), H - 1);
        const int wc = min(max(ww, 0), W - 1);
        off[k] = hc * W + wc;                       // clamped (safe) address
        sv[k] = valid ? Sb[(size_t)k * HW] : 0.0f;  // invalid taps contribute 0
    }

    const int c0 = blockIdx.z * (C / 4);
    const float* xb = x + (size_t)b * C * HW;
    const float* chb = ch + b * C * KK;
    float* ob = out + (size_t)b * C * HW;

    for (int c = c0; c < c0 + C / 4; ++c) {
        const float* xc = xb + (size_t)c * HW;
        float acc = 0.0f;
#pragma unroll
        for (int k = 0; k < KK; ++k) {
            // chb index uniform across lanes -> scalar load
            acc = fmaf(xc[off[k]], sv[k] * chb[c * KK + k], acc);
        }
        ob[(size_t)c * HW + p] = acc;  // coalesced along p
    }
}

extern "C" void kernel_launch(void* const* d_in, const int* in_sizes, int n_in,
                              void* d_out, int out_size, void* d_ws, size_t ws_size,
                              hipStream_t stream) {
    (void)in_sizes; (void)n_in; (void)out_size; (void)ws_size;
    const float* x  = (const float*)d_in[0];
    const float* Ws = (const float*)d_in[1];
    const float* bs = (const float*)d_in[2];
    const float* W1 = (const float*)d_in[3];
    const float* b1 = (const float*)d_in[4];
    const float* W2 = (const float*)d_in[5];
    const float* b2 = (const float*)d_in[6];
    float* out = (float*)d_out;
    float* ws  = (float*)d_ws;

    float* xm = ws + WS_XM;
    float* ch = ws + WS_CH;
    float* S  = ws + WS_S;

    k_mean<<<dim3(C, B), 256, 0, stream>>>(x, xm);
    k_spatial<<<dim3(HW / 256, B), 256, 0, stream>>>(x, Ws, bs, S);
    k_mlp<<<1, 512, 0, stream>>>(xm, W1, b1, W2, b2, ch);
    k_conv<<<dim3(HW / 256, B, 4), 256, 0, stream>>>(x, S, ch, out);
}

// Round 3
// 134.838 us; speedup vs baseline: 2.8084x; 1.1133x over previous
//
#include <hip/hip_runtime.h>

#define B 4
#define C 128
#define H 128
#define W 128
#define HW (H * W)
#define KK 9
#define MID 25

// Workspace layout (floats):
//   [0, 512)        xm      (B*C)   per-channel means
//   [1024, 5632)    ch      (B*C*KK) channel filter
//   [8192, 598016)  S       (B*KK*HW) spatial filter
#define WS_XM 0
#define WS_CH 1024
#define WS_S  8192

// K0: per-(b,c)-plane mean. grid (C, B), block 256. float4 loads, LDS reduce.
__global__ __launch_bounds__(256) void k_mean(
    const float* __restrict__ x, float* __restrict__ xm)
{
    const int c = blockIdx.x, b = blockIdx.y;
    const float4* plane = (const float4*)(x + ((size_t)b * C + c) * HW);
    float s = 0.0f;
#pragma unroll
    for (int i = 0; i < 16; ++i) {
        float4 v = plane[i * 256 + threadIdx.x];
        s += (v.x + v.y) + (v.z + v.w);
    }
#pragma unroll
    for (int off = 32; off > 0; off >>= 1) s += __shfl_down(s, off, 64);
    __shared__ float red[4];
    if ((threadIdx.x & 63) == 0) red[threadIdx.x >> 6] = s;
    __syncthreads();
    if (threadIdx.x == 0)
        xm[b * C + c] = ((red[0] + red[1]) + (red[2] + red[3])) * (1.0f / HW);
}

// K1: spatial filter sigmoid(x . Ws + bs).
// grid (HW/64, B), block 256 = 4 waves; each wave handles 64 pixels x 32 channels,
// fully unrolled (32 loads in flight), then LDS cross-wave reduce.
__global__ __launch_bounds__(256) void k_spatial(
    const float* __restrict__ x, const float* __restrict__ Ws,
    const float* __restrict__ bs, float* __restrict__ S)
{
    const int lane = threadIdx.x & 63;
    const int wave = threadIdx.x >> 6;
    const int b = blockIdx.y;
    const int p = blockIdx.x * 64 + lane;
    const float* xb = x + (size_t)b * C * HW + p;

    float acc[KK];
#pragma unroll
    for (int k = 0; k < KK; ++k) acc[k] = (wave == 0) ? bs[k] : 0.0f;

    const int cbase = wave * 32;
#pragma unroll
    for (int i = 0; i < 32; ++i) {
        const int c = cbase + i;                 // wave-uniform -> scalar Ws loads
        float v = xb[(size_t)c * HW];
#pragma unroll
        for (int k = 0; k < KK; ++k)
            acc[k] = fmaf(v, Ws[k * C + c], acc[k]);
    }

    __shared__ float red[3 * KK * 64];
    if (wave > 0) {
#pragma unroll
        for (int k = 0; k < KK; ++k)
            red[((wave - 1) * KK + k) * 64 + lane] = acc[k];
    }
    __syncthreads();
    if (wave == 0) {
#pragma unroll
        for (int k = 0; k < KK; ++k) {
            float a = acc[k] + red[(0 * KK + k) * 64 + lane]
                             + red[(1 * KK + k) * 64 + lane]
                             + red[(2 * KK + k) * 64 + lane];
            S[((size_t)(b * KK + k)) * HW + p] = 1.0f / (1.0f + __expf(-a));
        }
    }
}

// K2: channel MLP. Single block, 512 threads.
__global__ __launch_bounds__(512) void k_mlp(
    const float* __restrict__ xm, const float* __restrict__ W1,
    const float* __restrict__ b1, const float* __restrict__ W2,
    const float* __restrict__ b2, float* __restrict__ ch)
{
    __shared__ float xmean[B * C];
    __shared__ float hid[B * MID];
    const int tid = threadIdx.x;

    if (tid < B * C) xmean[tid] = xm[tid];
    __syncthreads();

    if (tid < B * MID) {
        const int b = tid / MID, m = tid % MID;
        float a = b1[m];
        for (int c = 0; c < C; ++c)
            a = fmaf(xmean[b * C + c], W1[m * C + c], a);
        hid[tid] = fmaxf(a, 0.0f);
    }
    __syncthreads();

    for (int idx = tid; idx < B * C * KK; idx += 512) {
        const int b = idx / (C * KK);
        const int o = idx % (C * KK);
        float a = b2[o];
#pragma unroll
        for (int m = 0; m < MID; ++m)
            a = fmaf(hid[b * MID + m], W2[o * MID + m], a);
        ch[idx] = 1.0f / (1.0f + __expf(-a));
    }
}

// K3: dynamic 3x3 conv. grid (HW/256, B, 8), block 256.
// One thread per pixel; z splits channels (16 each) -> 2048 blocks = 32 waves/CU.
__global__ __launch_bounds__(256) void k_conv(
    const float* __restrict__ x, const float* __restrict__ S,
    const float* __restrict__ ch, float* __restrict__ out)
{
    const int tid = threadIdx.x;
    const int b = blockIdx.y;
    const int p = blockIdx.x * 256 + tid;
    const int h = p / W, w = p % W;

    // 9 spatial-filter values for this pixel; fold tap validity into them.
    float sv[KK];
    int off[KK];
    const float* Sb = S + (size_t)b * KK * HW + p;
#pragma unroll
    for (int k = 0; k < KK; ++k) {
        const int di = k / 3 - 1, dj = k % 3 - 1;
        const int hh = h + di, ww = w + dj;
        const bool valid = (hh >= 0) & (hh < H) & (ww >= 0) & (ww < W);
        const int hc = min(max(hh, 0), H - 1);
        const int wc = min(max(ww, 0), W - 1);
        off[k] = hc * W + wc;                       // clamped (safe) address
        sv[k] = valid ? Sb[(size_t)k * HW] : 0.0f;  // invalid taps contribute 0
    }

    const int c0 = blockIdx.z * (C / 8);
    const float* xb = x + (size_t)b * C * HW;
    const float* chb = ch + b * C * KK;
    float* ob = out + (size_t)b * C * HW;

#pragma unroll 4
    for (int c = c0; c < c0 + C / 8; ++c) {
        const float* xc = xb + (size_t)c * HW;
        float acc = 0.0f;
#pragma unroll
        for (int k = 0; k < KK; ++k) {
            // chb index uniform across lanes -> scalar load
            acc = fmaf(xc[off[k]], sv[k] * chb[c * KK + k], acc);
        }
        ob[(size_t)c * HW + p] = acc;  // coalesced along p
    }
}

extern "C" void kernel_launch(void* const* d_in, const int* in_sizes, int n_in,
                              void* d_out, int out_size, void* d_ws, size_t ws_size,
                              hipStream_t stream) {
    (void)in_sizes; (void)n_in; (void)out_size; (void)ws_size;
    const float* x  = (const float*)d_in[0];
    const float* Ws = (const float*)d_in[1];
    const float* bs = (const float*)d_in[2];
    const float* W1 = (const float*)d_in[3];
    const float* b1 = (const float*)d_in[4];
    const float* W2 = (const float*)d_in[5];
    const float* b2 = (const float*)d_in[6];
    float* out = (float*)d_out;
    float* ws  = (float*)d_ws;

    float* xm = ws + WS_XM;
    float* ch = ws + WS_CH;
    float* S  = ws + WS_S;

    k_mean<<<dim3(C, B), 256, 0, stream>>>(x, xm);
    k_spatial<<<dim3(HW / 64, B), 256, 0, stream>>>(x, Ws, bs, S);
    k_mlp<<<1, 512, 0, stream>>>(xm, W1, b1, W2, b2, ch);
    k_conv<<<dim3(HW / 256, B, 8), 256, 0, stream>>>(x, S, ch, out);
}

// Round 4
// 126.957 us; speedup vs baseline: 2.9828x; 1.0621x over previous
//
#include <hip/hip_runtime.h>

#define B 4
#define C 128
#define H 128
#define W 128
#define HW (H * W)
#define KK 9
#define MID 25

#define SPATIAL_BLKS (HW / 64)   // 256 spatial blocks per batch

// Workspace layout (floats):
//   [0, 512)        xm      (B*C)   per-channel means
//   [1024, 5632)    ch      (B*C*KK) channel filter
//   [8192, 598016)  S       (B*KK*HW) spatial filter
#define WS_XM 0
#define WS_CH 1024
#define WS_S  8192

// K1: block-specialized fused kernel. grid (SPATIAL_BLKS + C, B), block 256.
//  - blocks [0, SPATIAL_BLKS): spatial filter sigmoid(x . Ws + bs).
//    4 waves split channels (32 each), fully unrolled, LDS cross-wave reduce.
//  - blocks [SPATIAL_BLKS, SPATIAL_BLKS+C): per-(b,c)-plane mean (overlaps
//    with spatial blocks instead of a serialized separate dispatch).
__global__ __launch_bounds__(256) void k_ms(
    const float* __restrict__ x, const float* __restrict__ Ws,
    const float* __restrict__ bs, float* __restrict__ xm,
    float* __restrict__ S)
{
    __shared__ float red[3 * KK * 64];
    const int b = blockIdx.y;

    if (blockIdx.x >= SPATIAL_BLKS) {
        // ---- mean path ----
        const int c = blockIdx.x - SPATIAL_BLKS;
        const float4* plane = (const float4*)(x + ((size_t)b * C + c) * HW);
        float s = 0.0f;
#pragma unroll
        for (int i = 0; i < 16; ++i) {
            float4 v = plane[i * 256 + threadIdx.x];
            s += (v.x + v.y) + (v.z + v.w);
        }
#pragma unroll
        for (int off = 32; off > 0; off >>= 1) s += __shfl_down(s, off, 64);
        if ((threadIdx.x & 63) == 0) red[threadIdx.x >> 6] = s;
        __syncthreads();
        if (threadIdx.x == 0)
            xm[b * C + c] = ((red[0] + red[1]) + (red[2] + red[3])) * (1.0f / HW);
        return;
    }

    // ---- spatial path ----
    const int lane = threadIdx.x & 63;
    const int wave = threadIdx.x >> 6;
    const int p = blockIdx.x * 64 + lane;
    const float* xb = x + (size_t)b * C * HW + p;

    float acc[KK];
#pragma unroll
    for (int k = 0; k < KK; ++k) acc[k] = (wave == 0) ? bs[k] : 0.0f;

    const int cbase = wave * 32;
#pragma unroll
    for (int i = 0; i < 32; ++i) {
        const int c = cbase + i;                 // wave-uniform -> scalar Ws loads
        float v = xb[(size_t)c * HW];
#pragma unroll
        for (int k = 0; k < KK; ++k)
            acc[k] = fmaf(v, Ws[k * C + c], acc[k]);
    }

    if (wave > 0) {
#pragma unroll
        for (int k = 0; k < KK; ++k)
            red[((wave - 1) * KK + k) * 64 + lane] = acc[k];
    }
    __syncthreads();
    if (wave == 0) {
#pragma unroll
        for (int k = 0; k < KK; ++k) {
            float a = acc[k] + red[(0 * KK + k) * 64 + lane]
                             + red[(1 * KK + k) * 64 + lane]
                             + red[(2 * KK + k) * 64 + lane];
            S[((size_t)(b * KK + k)) * HW + p] = 1.0f / (1.0f + __expf(-a));
        }
    }
}

// K2: channel MLP, parallelized. grid 18 blocks x 256 threads; each block
// redundantly computes hid (tiny) then 256 of the 4608 ch outputs.
__global__ __launch_bounds__(256) void k_mlp(
    const float* __restrict__ xm, const float* __restrict__ W1,
    const float* __restrict__ b1, const float* __restrict__ W2,
    const float* __restrict__ b2, float* __restrict__ ch)
{
    __shared__ float xmean[B * C];
    __shared__ float hid[B * MID];
    const int tid = threadIdx.x;

    for (int i = tid; i < B * C; i += 256) xmean[i] = xm[i];
    __syncthreads();

    if (tid < B * MID) {
        const int b = tid / MID, m = tid % MID;
        float a = b1[m];
#pragma unroll 8
        for (int c = 0; c < C; ++c)
            a = fmaf(xmean[b * C + c], W1[m * C + c], a);
        hid[tid] = fmaxf(a, 0.0f);
    }
    __syncthreads();

    const int idx = blockIdx.x * 256 + tid;   // 18*256 == B*C*KK == 4608
    const int b = idx / (C * KK);
    const int o = idx % (C * KK);
    float a = b2[o];
#pragma unroll
    for (int m = 0; m < MID; ++m)
        a = fmaf(hid[b * MID + m], W2[o * MID + m], a);
    ch[idx] = 1.0f / (1.0f + __expf(-a));
}

// K3: dynamic 3x3 conv, float4-vectorized: each thread owns 4 consecutive
// pixels of one row. grid (HW/1024, B, 16), block 256; z splits channels (8 each).
// Per channel: 3 aligned float4 row loads + 6 edge scalars (vs 36 scalar taps).
__global__ __launch_bounds__(256) void k_conv(
    const float* __restrict__ x, const float* __restrict__ S,
    const float* __restrict__ ch, float* __restrict__ out)
{
    const int tid = threadIdx.x;
    const int b = blockIdx.y;
    const int p0 = (blockIdx.x * 256 + tid) * 4;
    const int h = p0 >> 7;          // /W
    const int w0 = p0 & (W - 1);    // multiple of 4

    // 9 per-pixel spatial-filter vectors; fold row/col tap validity into them.
    float4 sv[KK];
    const float* Sb = S + (size_t)b * KK * HW + p0;
#pragma unroll
    for (int k = 0; k < KK; ++k) {
        const int di = k / 3 - 1, dj = k % 3 - 1;
        const int hh = h + di;
        float4 s4 = *(const float4*)(Sb + (size_t)k * HW);
        if (hh < 0 || hh >= H) s4 = make_float4(0.f, 0.f, 0.f, 0.f);
        if (dj == -1 && w0 == 0)     s4.x = 0.f;   // col -1
        if (dj == +1 && w0 == W - 4) s4.w = 0.f;   // col W
        sv[k] = s4;
    }

    const int r0 = max(h - 1, 0), r2 = min(h + 1, H - 1);
    const int rowoff[3] = { r0 * W + w0, h * W + w0, r2 * W + w0 };
    const int loff = (w0 > 0) ? -1 : 0;       // masked by sv when w0==0
    const int roff = (w0 < W - 4) ? 4 : 0;    // masked by sv when w0==W-4

    const int c0 = blockIdx.z * (C / 16);
    const float* xb = x + (size_t)b * C * HW;
    const float* chb = ch + b * C * KK;
    float* ob = out + (size_t)b * C * HW + p0;

    for (int c = c0; c < c0 + C / 16; ++c) {
        const float* xc = xb + (size_t)c * HW;
        float4 Cx[3];
        float  Lw[3], Rx[3];
#pragma unroll
        for (int r = 0; r < 3; ++r) {
            const float* bp = xc + rowoff[r];
            Cx[r] = *(const float4*)bp;
            Lw[r] = bp[loff];
            Rx[r] = bp[roff];
        }
        float4 a = make_float4(0.f, 0.f, 0.f, 0.f);
#pragma unroll
        for (int k = 0; k < KK; ++k) {
            const int r = k / 3, dj = k % 3 - 1;
            float4 t;
            if (dj == -1)     t = make_float4(Lw[r], Cx[r].x, Cx[r].y, Cx[r].z);
            else if (dj == 0) t = Cx[r];
            else              t = make_float4(Cx[r].y, Cx[r].z, Cx[r].w, Rx[r]);
            const float cf = chb[c * KK + k];   // uniform -> scalar load
            a.x = fmaf(t.x, sv[k].x * cf, a.x);
            a.y = fmaf(t.y, sv[k].y * cf, a.y);
            a.z = fmaf(t.z, sv[k].z * cf, a.z);
            a.w = fmaf(t.w, sv[k].w * cf, a.w);
        }
        *(float4*)(ob + (size_t)c * HW) = a;    // coalesced 16B store
    }
}

extern "C" void kernel_launch(void* const* d_in, const int* in_sizes, int n_in,
                              void* d_out, int out_size, void* d_ws, size_t ws_size,
                              hipStream_t stream) {
    (void)in_sizes; (void)n_in; (void)out_size; (void)ws_size;
    const float* x  = (const float*)d_in[0];
    const float* Ws = (const float*)d_in[1];
    const float* bs = (const float*)d_in[2];
    const float* W1 = (const float*)d_in[3];
    const float* b1 = (const float*)d_in[4];
    const float* W2 = (const float*)d_in[5];
    const float* b2 = (const float*)d_in[6];
    float* out = (float*)d_out;
    float* ws  = (float*)d_ws;

    float* xm = ws + WS_XM;
    float* ch = ws + WS_CH;
    float* S  = ws + WS_S;

    k_ms<<<dim3(SPATIAL_BLKS + C, B), 256, 0, stream>>>(x, Ws, bs, xm, S);
    k_mlp<<<18, 256, 0, stream>>>(xm, W1, b1, W2, b2, ch);
    k_conv<<<dim3(HW / 1024, B, 16), 256, 0, stream>>>(x, S, ch, out);
}